// Round 1
// 123.865 us; speedup vs baseline: 1.1973x; 1.1973x over previous
//
#include <hip/hip_runtime.h>
#include <hip/hip_bf16.h>
#include <math.h>

using bf16 = __hip_bfloat16;
typedef short short8 __attribute__((ext_vector_type(8)));   // 8 bf16 = 4 VGPRs
typedef float f32x4 __attribute__((ext_vector_type(4)));    // MFMA 16x16 acc

#define MFMA16 __builtin_amdgcn_mfma_f32_16x16x32_bf16
#define S_ 8192

// swizzled LDS addressing: 256B rows, 16 x 16B chunks, XOR swizzle.
__device__ __forceinline__ int sw(int r, int chunk) {
  return r * 256 + (((chunk) ^ (r & 15)) << 4);
}

__device__ __forceinline__ float gelu_exact(float y) {
  return 0.5f * y * (1.0f + erff(y * 0.70710678118654752f));
}

__device__ __forceinline__ unsigned pack2(float a, float b) {
  unsigned ra = (unsigned)__bfloat16_as_ushort(__float2bfloat16(a));
  unsigned rb = (unsigned)__bfloat16_as_ushort(__float2bfloat16(b));
  return ra | (rb << 16);
}

// async global->LDS, 16B per lane (dest must be wave-uniform base + lane*16)
__device__ __forceinline__ void gl_lds16(const char* g, char* l) {
  __builtin_amdgcn_global_load_lds(
      (const __attribute__((address_space(1))) void*)g,
      (__attribute__((address_space(3))) void*)l, 16, 0, 0);
}

// stage one 32KB fragment-blocked weight matrix into LDS (512 threads)
__device__ __forceinline__ void stage_w(const char* g, char* l, int tid) {
#pragma unroll
  for (int i = 0; i < 4; ++i)
    gl_lds16(g + i * 8192 + tid * 16, l + i * 8192 + tid * 16);
}

// ---- weight convert to FRAGMENT-BLOCKED layout ------------------------------
// Fragment gf = ((ct*4 + t)*4 + quad)*16 + l15 holds B[k][n] with
// n = ct*16+l15, k = t*32 + quad*8 + j (j=0..7).
__global__ void transw(const float* __restrict__ wq, const float* __restrict__ wk,
                       const float* __restrict__ wv, const float* __restrict__ wo,
                       bf16* __restrict__ wt) {
  __shared__ float smf[128 * 33];           // 128 k x 32 n slice, pad 33
  int m = blockIdx.x >> 2, sl = blockIdx.x & 3;
  const float* W = (m == 0) ? wq : (m == 1) ? wk : (m == 2) ? wv : wo;
  for (int i = 0; i < 4; ++i) {
    int u = threadIdx.x + i * 256;          // 0..1023 float4 units
    int k = u >> 3, cg = u & 7;
    float4 v = *(const float4*)(W + k * 128 + sl * 32 + cg * 4);
    smf[k * 33 + cg * 4 + 0] = v.x;
    smf[k * 33 + cg * 4 + 1] = v.y;
    smf[k * 33 + cg * 4 + 2] = v.z;
    smf[k * 33 + cg * 4 + 3] = v.w;
  }
  __syncthreads();
  for (int i = 0; i < 2; ++i) {
    int f = threadIdx.x + i * 256;          // 0..511 local frags
    int l15 = f & 15, q = (f >> 4) & 3, t = (f >> 6) & 3, ctl = (f >> 8) & 1;
    int ct = sl * 2 + ctl;
    int gf = ((ct * 4 + t) * 4 + q) * 16 + l15;
    int k0 = t * 32 + q * 8, nl = ctl * 16 + l15;
    bf16 tmp[8];
#pragma unroll
    for (int j = 0; j < 8; ++j)
      tmp[j] = __float2bfloat16(smf[(k0 + j) * 33 + nl]);
    *(uint4*)(wt + m * 16384 + gf * 8) = *(const uint4*)tmp;
  }
}

// ---- mm helpers ------------------------------------------------------------
__device__ __forceinline__ void clr8(f32x4 acc[8]) {
#pragma unroll
  for (int j = 0; j < 8; ++j) acc[j] = (f32x4){0.f, 0.f, 0.f, 0.f};
}

// A = two register fragment strips, B = fragment-blocked weight in LDS.
// Each b-frag load feeds TWO MFMAs (strip0 + strip1).
__device__ __forceinline__ void mm_w2(const short8 a0[4], const short8 a1[4],
                                      const char* Wb, int l15, int quad,
                                      f32x4 accA[8], f32x4 accB[8]) {
#pragma unroll
  for (int t = 0; t < 4; ++t) {
    short8 bfr[8];
#pragma unroll
    for (int ct = 0; ct < 8; ++ct)
      bfr[ct] = *(const short8*)(Wb + ((((ct * 4 + t) * 4 + quad) * 16 + l15) << 4));
#pragma unroll
    for (int ct = 0; ct < 8; ++ct) {
      accA[ct] = MFMA16(a0[t], bfr[ct], accA[ct], 0, 0, 0);
      accB[ct] = MFMA16(a1[t], bfr[ct], accB[ct], 0, 0, 0);
    }
  }
}

// A = two LDS strips (swizzled), B = fragment-blocked weight in LDS.
__device__ __forceinline__ void mm_sw2(const char* sA, const char* sB, const char* Wb,
                                       int l15, int quad, f32x4 accA[8], f32x4 accB[8]) {
#pragma unroll
  for (int t = 0; t < 4; ++t) {
    short8 a0 = *(const short8*)(sA + sw(l15, 4 * t + quad));
    short8 a1 = *(const short8*)(sB + sw(l15, 4 * t + quad));
    short8 bfr[8];
#pragma unroll
    for (int ct = 0; ct < 8; ++ct)
      bfr[ct] = *(const short8*)(Wb + ((((ct * 4 + t) * 4 + quad) * 16 + l15) << 4));
#pragma unroll
    for (int ct = 0; ct < 8; ++ct) {
      accA[ct] = MFMA16(a0, bfr[ct], accA[ct], 0, 0, 0);
      accB[ct] = MFMA16(a1, bfr[ct], accB[ct], 0, 0, 0);
    }
  }
}

// A = two LDS strips, B = LDS tile stored [n][k] swizzled (K or V^T)
__device__ __forceinline__ void mm_l2(const char* sA, const char* sB, const char* tB,
                                      int l15, int quad, f32x4 accA[8], f32x4 accB[8]) {
#pragma unroll
  for (int t = 0; t < 4; ++t) {
    short8 a0 = *(const short8*)(sA + sw(l15, 4 * t + quad));
    short8 a1 = *(const short8*)(sB + sw(l15, 4 * t + quad));
    short8 bfr[8];
#pragma unroll
    for (int ct = 0; ct < 8; ++ct)
      bfr[ct] = *(const short8*)(tB + sw(ct * 16 + l15, 4 * t + quad));
#pragma unroll
    for (int ct = 0; ct < 8; ++ct) {
      accA[ct] = MFMA16(a0, bfr[ct], accA[ct], 0, 0, 0);
      accB[ct] = MFMA16(a1, bfr[ct], accB[ct], 0, 0, 0);
    }
  }
}

// C/D strip -> row-major swizzled 16-row tile at base, optional row scale
__device__ __forceinline__ void store_strip16(char* tile, int l15, int quad,
                                              const f32x4 acc[8], const float* rs) {
#pragma unroll
  for (int ct = 0; ct < 8; ++ct) {
    int col = ct * 16 + l15;
#pragma unroll
    for (int r = 0; r < 4; ++r) {
      float v = acc[ct][r];
      if (rs) v *= rs[r];
      *(bf16*)(tile + sw(quad * 4 + r, col >> 3) + (col & 7) * 2) = __float2bfloat16(v);
    }
  }
}

__device__ __forceinline__ void softmax_rows(f32x4 acc[8], float inv[4]) {
  const float sscale = 0.08838834764831845f;   // 1/sqrt(128)
#pragma unroll
  for (int r = 0; r < 4; ++r) {
    float sum = 0.f;
#pragma unroll
    for (int ct = 0; ct < 8; ++ct) {
      float v = __expf(acc[ct][r] * sscale);
      acc[ct][r] = v;
      sum += v;
    }
#pragma unroll
    for (int off = 8; off; off >>= 1) sum += __shfl_xor(sum, off, 64);
    inv[r] = 1.0f / sum;
  }
}

// LN + GELU + coalesced store for one 16-row strip (fs = strip's own 4KB)
__device__ __forceinline__ void ln_gelu_store(const f32x4 acc[8], char* strip,
                                              float* outrow, int l15, int quad,
                                              const float gg[8], const float bb[8]) {
  float mean[4], rstd[4];
#pragma unroll
  for (int r = 0; r < 4; ++r) {
    float sum = 0.f;
#pragma unroll
    for (int ct = 0; ct < 8; ++ct) sum += acc[ct][r];
#pragma unroll
    for (int off = 8; off; off >>= 1) sum += __shfl_xor(sum, off, 64);
    mean[r] = sum * (1.0f / 128.0f);
    float sq = 0.f;
#pragma unroll
    for (int ct = 0; ct < 8; ++ct) { float d = acc[ct][r] - mean[r]; sq += d * d; }
#pragma unroll
    for (int off = 8; off; off >>= 1) sq += __shfl_xor(sq, off, 64);
    rstd[r] = rsqrtf(sq * (1.0f / 128.0f) + 1e-5f);
  }
  float* fs = (float*)strip;
  const int lane = quad * 16 + l15;
#pragma unroll
  for (int p = 0; p < 2; ++p) {
    asm volatile("" ::: "memory");          // fence vs prior strip reads / pass
#pragma unroll
    for (int rr = 0; rr < 2; ++rr) {
      int r = 2 * p + rr;
      int s = quad * 2 + rr;
#pragma unroll
      for (int ct = 0; ct < 8; ++ct) {
        float y = (acc[ct][r] - mean[r]) * rstd[r] * gg[ct] + bb[ct];
        fs[s * 128 + ct * 16 + l15] = gelu_exact(y);
      }
    }
    asm volatile("" ::: "memory");          // f32 writes -> float4 reads
#pragma unroll
    for (int j = 0; j < 4; ++j) {
      int u = j * 64 + lane;                // 0..255 float4 units
      int s2 = u >> 5, coff = (u & 31) * 4;
      int grow = (s2 >> 1) * 4 + 2 * p + (s2 & 1);
      *(float4*)(outrow + (size_t)grow * 128 + coff) = *(const float4*)(fs + s2 * 128 + coff);
    }
  }
}

// ---- fused kernel: 2 windows/block, 8 waves x 32 rows, LDS-staged weights ---
// LDS map (160 KB): [0,64K) wave strips (wave*8K, 2x4K) | [64K,128K) K/V^T
// tiles (win*32K) | [128K,160K) weight buffer. Weight stages at P0/P2/P4/P6
// alternate with reads at P1/P3/P5/P7 -> single shared buffer, no ping-pong.
__global__ __launch_bounds__(512, 2) void attn_fused(
    const float* __restrict__ x, const bf16* __restrict__ wt,
    const float* __restrict__ gamma, const float* __restrict__ beta,
    float* __restrict__ out) {
  __shared__ uint4 ldsbuf[10240];           // 160 KB
  char* lds = (char*)ldsbuf;
  char* t_s = lds;                          // strips
  char* t_k = lds + 65536;                  // K tiles (-> V^T)
  char* t_w = lds + 131072;                 // weight buffer (32 KB)

  const int tid = threadIdx.x;
  const int wave = tid >> 6, lane = tid & 63;
  const int l15 = lane & 15, quad = lane >> 4;
  const int win = wave >> 2, widx = wave & 3;
  const int b = blockIdx.x >> 5, sb = blockIdx.x & 31;

  char* myk = t_k + win * 32768;
  char* s0 = t_s + wave * 8192;
  char* s1 = s0 + 4096;
  const int r0 = widx * 32;                 // window-local row of strip0
  const int localrow = win * 128 + r0;      // block-local row of strip0

  const float* xb = x + ((size_t)b * S_ + (size_t)sb * 256) * 128;
  float* outb = out + ((size_t)b * 2 * S_ + (size_t)sb * 256) * 128;

  // ---- P0: stage Wq; X fragments global -> registers (2 strips) ----
  stage_w((const char*)wt, t_w, tid);
  short8 ax0[4], ax1[4];
  {
    const float* xr0 = xb + (size_t)(localrow + l15) * 128 + quad * 8;
    const float* xr1 = xr0 + 16 * 128;
#pragma unroll
    for (int t = 0; t < 4; ++t) {
      float4 f0 = *(const float4*)(xr0 + t * 32);
      float4 f1 = *(const float4*)(xr0 + t * 32 + 4);
      float4 f2 = *(const float4*)(xr1 + t * 32);
      float4 f3 = *(const float4*)(xr1 + t * 32 + 4);
      union { unsigned u[4]; short8 s; } pa, pb;
      pa.u[0] = pack2(f0.x, f0.y); pa.u[1] = pack2(f0.z, f0.w);
      pa.u[2] = pack2(f1.x, f1.y); pa.u[3] = pack2(f1.z, f1.w);
      pb.u[0] = pack2(f2.x, f2.y); pb.u[1] = pack2(f2.z, f2.w);
      pb.u[2] = pack2(f3.x, f3.y); pb.u[3] = pack2(f3.z, f3.w);
      ax0[t] = pa.s; ax1[t] = pb.s;
    }
  }
  __syncthreads();

  f32x4 accA[8], accB[8];

  // ---- P1: Q = X @ Wq -> own strips ----
  clr8(accA); clr8(accB);
  mm_w2(ax0, ax1, t_w, l15, quad, accA, accB);
  store_strip16(s0, l15, quad, accA, nullptr);
  store_strip16(s1, l15, quad, accB, nullptr);
  __syncthreads();

  // ---- P2: stage Wk; second-half fill out2 = gelu(beta) broadcast ----
  stage_w((const char*)(wt + 16384), t_w, tid);
  {
    float* o2 = out + ((size_t)b * 2 * S_ + (size_t)(S_ + sb * 256)) * 128;
    int c0 = (tid * 4) & 127;
    float4 bv = *(const float4*)(beta + c0);
    float4 gv;
    gv.x = gelu_exact(bv.x); gv.y = gelu_exact(bv.y);
    gv.z = gelu_exact(bv.z); gv.w = gelu_exact(bv.w);
#pragma unroll
    for (int j = 0; j < 16; ++j)
      *(float4*)(o2 + tid * 4 + j * 2048) = gv;
  }
  __syncthreads();

  // ---- P3: K = X @ Wk -> shared K tile ----
  clr8(accA); clr8(accB);
  mm_w2(ax0, ax1, t_w, l15, quad, accA, accB);
  store_strip16(myk + r0 * 256, l15, quad, accA, nullptr);
  store_strip16(myk + (r0 + 16) * 256, l15, quad, accB, nullptr);
  __syncthreads();

  // ---- P4: stage Wv (hidden); S = Q @ K^T; softmax; P -> strips ----
  stage_w((const char*)(wt + 2 * 16384), t_w, tid);
  clr8(accA); clr8(accB);
  mm_l2(s0, s1, myk, l15, quad, accA, accB);
  float inv0[4], inv1[4];
  softmax_rows(accA, inv0);
  softmax_rows(accB, inv1);
  store_strip16(s0, l15, quad, accA, nullptr);
  store_strip16(s1, l15, quad, accB, nullptr);
  __syncthreads();

  // ---- P5: V = X @ Wv; publish V^T over K tile ----
  clr8(accA); clr8(accB);
  mm_w2(ax0, ax1, t_w, l15, quad, accA, accB);
  {
    int seq0 = r0 + quad * 4;
    int seq1 = r0 + 16 + quad * 4;
#pragma unroll
    for (int ct = 0; ct < 8; ++ct) {
      int d = ct * 16 + l15;
      unsigned pa[2] = {pack2(accA[ct][0], accA[ct][1]),
                        pack2(accA[ct][2], accA[ct][3])};
      unsigned pb[2] = {pack2(accB[ct][0], accB[ct][1]),
                        pack2(accB[ct][2], accB[ct][3])};
      *(uint2*)(myk + sw(d, seq0 >> 3) + (seq0 & 7) * 2) = *(const uint2*)pa;
      *(uint2*)(myk + sw(d, seq1 >> 3) + (seq1 & 7) * 2) = *(const uint2*)pb;
    }
  }
  __syncthreads();

  // ---- P6: stage Wo (hidden); O = P @ V^T (fold 1/rowsum) -> strips ----
  stage_w((const char*)(wt + 3 * 16384), t_w, tid);
  clr8(accA); clr8(accB);
  mm_l2(s0, s1, myk, l15, quad, accA, accB);
  store_strip16(s0, l15, quad, accA, inv0);
  store_strip16(s1, l15, quad, accB, inv1);
  __syncthreads();

  // ---- P7: H = O @ Wo; LayerNorm + GELU + coalesced store ----
  clr8(accA); clr8(accB);
  mm_sw2(s0, s1, t_w, l15, quad, accA, accB);
  float gg[8], bb[8];
#pragma unroll
  for (int ct = 0; ct < 8; ++ct) {
    gg[ct] = gamma[ct * 16 + l15];
    bb[ct] = beta[ct * 16 + l15];
  }
  ln_gelu_store(accA, s0, outb + (size_t)localrow * 128, l15, quad, gg, bb);
  ln_gelu_store(accB, s1, outb + (size_t)(localrow + 16) * 128, l15, quad, gg, bb);
}

extern "C" void kernel_launch(void* const* d_in, const int* in_sizes, int n_in,
                              void* d_out, int out_size, void* d_ws, size_t ws_size,
                              hipStream_t stream) {
  const float* x     = (const float*)d_in[0];
  const float* wq    = (const float*)d_in[1];
  const float* wk    = (const float*)d_in[2];
  const float* wv    = (const float*)d_in[3];
  const float* wo    = (const float*)d_in[4];
  const float* gamma = (const float*)d_in[5];
  const float* beta  = (const float*)d_in[6];
  float* out = (float*)d_out;
  bf16* wt  = (bf16*)d_ws;                  // 4 x 128 x 128 bf16 = 128 KB

  transw<<<16, 256, 0, stream>>>(wq, wk, wv, wo, wt);
  attn_fused<<<256, 512, 0, stream>>>(x, wt, gamma, beta, out);
}